// Round 2
// baseline (30965.399 us; speedup 1.0000x reference)
//
#include <hip/hip_runtime.h>

typedef _Float16 half8 __attribute__((ext_vector_type(8)));
typedef float f32x4 __attribute__((ext_vector_type(4)));

#define MFMA(a,b,c) __builtin_amdgcn_mfma_f32_16x16x32_f16((a),(b),(c),0,0,0)

// packed-weight tile bases (1 tile = 16x16-output x 32-K fragment = 1024B)
#define TB_X    0      // W_in[0:256,:]   : 32 nt x 8 ks
#define TB_GI   256    // W_ih^T          : 96 nt x 16 ks
#define TB_GH   1792   // W_hh^T          : 96 nt x 16 ks
#define TB_O1H  3328   // W_o1[0:512,:]   : 32 nt x 16 ks
#define TB_O1C  3840   // W_o1[512:768,:] : 32 nt x 8 ks
#define TB_O2   4096   // W_o2            : 4 nt x 16 ks
#define NTILES  4160

#define WS_ETAB (NTILES*1024)          // 4,259,840 bytes
#define WS_H0   (WS_ETAB + 64*512*4)   // +131,072; h0w itself is 1024*512*4 = 2 MB

// ---------------- weight packing into MFMA B-fragment order ----------------
__global__ void pack_k(const float* __restrict__ W_in, const float* __restrict__ W_ih,
                       const float* __restrict__ W_hh, const float* __restrict__ W_o1,
                       const float* __restrict__ W_o2, _Float16* __restrict__ pk)
{
  int ti = blockIdx.x, lane = threadIdx.x;
  int seg = 0, nt = 0, ks = 0, r;
  if (ti < TB_GI)        { seg = 0; r = ti;          nt = r >> 3; ks = r & 7;  }
  else if (ti < TB_GH)   { seg = 1; r = ti - TB_GI;  nt = r >> 4; ks = r & 15; }
  else if (ti < TB_O1H)  { seg = 2; r = ti - TB_GH;  nt = r >> 4; ks = r & 15; }
  else if (ti < TB_O1C)  { seg = 3; r = ti - TB_O1H; nt = r >> 4; ks = r & 15; }
  else if (ti < TB_O2)   { seg = 4; r = ti - TB_O1C; nt = r >> 3; ks = r & 7;  }
  else                   { seg = 5; r = ti - TB_O2;  nt = r >> 4; ks = r & 15; }
  int n  = nt*16 + (lane & 15);
  int kb = ks*32 + (lane >> 4)*8;
  half8 v;
  #pragma unroll
  for (int e = 0; e < 8; e++){
    int k = kb + e; float f;
    if      (seg == 0) f = W_in[k*512 + n];
    else if (seg == 1) f = W_ih[n*512 + k];       // transpose: B[k][n]=W_ih[n][k]
    else if (seg == 2) f = W_hh[n*512 + k];
    else if (seg == 3) f = W_o1[k*512 + n];
    else if (seg == 4) f = W_o1[(512 + k)*512 + n];
    else               f = W_o2[k*64 + n];
    v[e] = (_Float16)f;
  }
  *(half8*)(pk + (long)ti*512 + lane*8) = v;
}

// ---------------- Etab[e][j] = E[e,:] @ W_in[256:512, j] + b_in[j] ----------------
__global__ void etab_k(const float* __restrict__ E, const float* __restrict__ W_in,
                       const float* __restrict__ b_in, float* __restrict__ Etab)
{
  int e = blockIdx.x, tid = threadIdx.x;
  __shared__ float er[256];
  if (tid < 256) er[tid] = E[e*256 + tid];
  __syncthreads();
  for (int j = tid; j < 512; j += 256){
    float acc = b_in[j];
    for (int k = 0; k < 256; k++) acc += er[k] * W_in[(256 + k)*512 + j];
    Etab[e*512 + j] = acc;
  }
}

// ---------------- h0 = tanh([ctx_mean, hist_emb] @ W_init + b_init), fp32 ----------------
__global__ __launch_bounds__(512) void h0_k(const float* __restrict__ ctx,
    const int* __restrict__ bh, const float* __restrict__ E,
    const float* __restrict__ W_init, const float* __restrict__ b_init,
    float* __restrict__ h0w)
{
  int b0 = blockIdx.x * 16, tid = threadIdx.x;
  __shared__ float cat[16][512];
  int c = tid & 255, rh = tid >> 8;
  for (int rr = 0; rr < 8; rr++){
    int r2 = rh*8 + rr;
    const float* p = ctx + ((b0 + r2)*128)*256 + c;
    float acc = 0.f;
    for (int t = 0; t < 128; t++) acc += p[t*256];
    cat[r2][c] = acc * (1.f/128.f);
    float s = 0.f;
    #pragma unroll
    for (int hh = 0; hh < 8; hh++){
      int e = bh[(b0 + r2)*8 + hh];
      s += E[e*256 + c];
    }
    cat[r2][256 + c] = s * 0.125f;
  }
  __syncthreads();
  int j = tid;
  float acc[16];
  #pragma unroll
  for (int r2 = 0; r2 < 16; r2++) acc[r2] = b_init[j];
  for (int k = 0; k < 512; k++){
    float wv = W_init[k*512 + j];
    #pragma unroll
    for (int r2 = 0; r2 < 16; r2++) acc[r2] += cat[r2][k] * wv;
  }
  #pragma unroll
  for (int r2 = 0; r2 < 16; r2++) h0w[(b0 + r2)*512 + j] = tanhf(acc[r2]);
}

// ---------------- main persistent scan kernel: 64 WGs x 512 thr, 16 rows each ----------------
#define AFRAG(buf, base, ks) (*(const half8*)((const char*)(buf) + ((((base) + (ks)*64)) ^ aswz)))
#define WSTORE(buf, row, j, val) \
  *(_Float16*)((char*)(buf) + ((((row)*1024 + (j)*2)) ^ ((((row)&7))<<4))) = (_Float16)(val)

__global__ __launch_bounds__(512, 2) void main_k(
    const _Float16* __restrict__ pk, const float* __restrict__ Etab,
    const float* __restrict__ h0w, const float* __restrict__ ctx,
    const int* __restrict__ bh, const float* __restrict__ b_ih,
    const float* __restrict__ b_hh, const float* __restrict__ lng,
    const float* __restrict__ lnb, const float* __restrict__ b_o1,
    const float* __restrict__ b_o2, float* __restrict__ out)
{
  const int g = blockIdx.x, tid = threadIdx.x;
  const int w = tid >> 6, lane = tid & 63, lo = lane & 15, hi = lane >> 4;
  const int r0 = g*16;

  __shared__ __align__(16) _Float16 h_s [16*512];  // h_{t-1}, f16 (A for gh)
  __shared__ __align__(16) _Float16 xh_s[16*512];  // x, then hidden (A for gi / o2)
  __shared__ __align__(16) _Float16 hn_s[16*512];  // layernorm(h) (A for o1)
  __shared__ __align__(16) _Float16 c_s [16*256];  // ctx_t f16 (A for x / o1c)
  __shared__ float lg_s[16*64];
  __shared__ float stats[8][4][4][2];
  __shared__ float murs[16][2];
  __shared__ int   pb[16];

  float bihr[4],bihz[4],bihn[4],bhhr[4],bhhz[4],bhhn[4],bo1v[4],lngv[4],lnbv[4];
  #pragma unroll
  for (int i = 0; i < 4; i++){
    int j = w*64 + i*16 + lo;
    bihr[i]=b_ih[j];     bihz[i]=b_ih[512+j]; bihn[i]=b_ih[1024+j];
    bhhr[i]=b_hh[j];     bhhz[i]=b_hh[512+j]; bhhn[i]=b_hh[1024+j];
    bo1v[i]=b_o1[j];     lngv[i]=lng[j];      lnbv[i]=lnb[j];
  }
  const float bo2v = (w < 4) ? b_o2[w*16 + lo] : 0.f;

  // h state in fp32 registers: wave w owns cols [w*64, w*64+64), lane holds 4 rows x 4 col-tiles
  float hreg[4][4];
  #pragma unroll
  for (int i = 0; i < 4; i++)
    #pragma unroll
    for (int rr = 0; rr < 4; rr++)
      hreg[i][rr] = h0w[(r0 + hi*4 + rr)*512 + w*64 + i*16 + lo];

  // stage h0 -> h_s (f16, swizzled)
  #pragma unroll
  for (int c2 = 0; c2 < 2; c2++){
    int ch = tid*2 + c2, rr = ch >> 6, c8 = ch & 63;
    const float* p = h0w + (r0 + rr)*512 + c8*8;
    half8 v;
    #pragma unroll
    for (int e = 0; e < 8; e++) v[e] = (_Float16)p[e];
    *(half8*)((char*)h_s + (((rr*1024 + c8*16)) ^ ((rr&7)<<4))) = v;
  }
  if (tid < 16) pb[tid] = bh[(r0 + tid)*8 + 7];
  __syncthreads();

  const int aswz  = (lo & 7) << 4;
  const int abase = lo*1024 + hi*16;
  const int cbase = lo*512  + hi*16;
  const half8* PK = (const half8*)pk;

  #pragma unroll 1
  for (int t = 0; t < 128; t++){
    // ---- A1: stage ctx_t (f32 -> f16 LDS, swizzled) ----
    {
      int rr = tid >> 5, c8 = tid & 31;
      const float* p = ctx + ((r0 + rr)*128 + t)*256 + c8*8;
      half8 v;
      #pragma unroll
      for (int e = 0; e < 8; e++) v[e] = (_Float16)p[e];
      *(half8*)((char*)c_s + (((rr*512 + c8*16)) ^ ((rr&7)<<4))) = v;
    }
    __syncthreads();

    // ---- A2: x = relu(ctx @ W_in_top + Etab[pb]) ----
    #pragma unroll
    for (int i = 0; i < 4; i++){
      f32x4 acc = {0.f,0.f,0.f,0.f};
      #pragma unroll
      for (int ks = 0; ks < 8; ks++){
        half8 a = AFRAG(c_s, cbase, ks);
        half8 b = PK[(TB_X + (w*4+i)*8 + ks)*64 + lane];
        acc = MFMA(a, b, acc);
      }
      #pragma unroll
      for (int rr = 0; rr < 4; rr++){
        int row = hi*4 + rr, j = w*64 + i*16 + lo;
        float v = acc[rr] + Etab[pb[row]*512 + j];
        WSTORE(xh_s, row, j, fmaxf(v, 0.f));
      }
    }
    __syncthreads();

    // ---- B: gi/gh MFMA + GRU gates (fp32) ----
    float srow[4] = {0,0,0,0}, sqrow[4] = {0,0,0,0};
    #pragma unroll
    for (int i = 0; i < 4; i++){
      f32x4 ai0={0,0,0,0}, ai1={0,0,0,0}, ai2={0,0,0,0};
      f32x4 ah0={0,0,0,0}, ah1={0,0,0,0}, ah2={0,0,0,0};
      #pragma unroll
      for (int ks = 0; ks < 16; ks++){
        half8 ax = AFRAG(xh_s, abase, ks);
        half8 ah = AFRAG(h_s,  abase, ks);
        ai0 = MFMA(ax, PK[(TB_GI + (     w*4+i)*16 + ks)*64 + lane], ai0);
        ai1 = MFMA(ax, PK[(TB_GI + (32 + w*4+i)*16 + ks)*64 + lane], ai1);
        ai2 = MFMA(ax, PK[(TB_GI + (64 + w*4+i)*16 + ks)*64 + lane], ai2);
        ah0 = MFMA(ah, PK[(TB_GH + (     w*4+i)*16 + ks)*64 + lane], ah0);
        ah1 = MFMA(ah, PK[(TB_GH + (32 + w*4+i)*16 + ks)*64 + lane], ah1);
        ah2 = MFMA(ah, PK[(TB_GH + (64 + w*4+i)*16 + ks)*64 + lane], ah2);
      }
      #pragma unroll
      for (int rr = 0; rr < 4; rr++){
        float ir = ai0[rr]+bihr[i], iz = ai1[rr]+bihz[i], inn = ai2[rr]+bihn[i];
        float hr = ah0[rr]+bhhr[i], hz = ah1[rr]+bhhz[i], hnn = ah2[rr]+bhhn[i];
        float rg = 1.f/(1.f + __expf(-(ir+hr)));
        float zg = 1.f/(1.f + __expf(-(iz+hz)));
        float aa = inn + rg*hnn;
        float ea = __expf(-2.f*fabsf(aa));
        float th = (1.f - ea)/(1.f + ea);
        float ng = (aa < 0.f) ? -th : th;
        float hv = (1.f - zg)*ng + zg*hreg[i][rr];
        hreg[i][rr] = hv;
        srow[rr] += hv; sqrow[rr] += hv*hv;
      }
    }
    #pragma unroll
    for (int d = 1; d < 16; d <<= 1){
      #pragma unroll
      for (int rr = 0; rr < 4; rr++){
        srow[rr]  += __shfl_xor(srow[rr],  d);
        sqrow[rr] += __shfl_xor(sqrow[rr], d);
      }
    }
    if (lo == 0){
      #pragma unroll
      for (int rr = 0; rr < 4; rr++){
        stats[w][hi][rr][0] = srow[rr];
        stats[w][hi][rr][1] = sqrow[rr];
      }
    }
    __syncthreads();
    if (w == 0 && lane < 16){
      float s = 0.f, q = 0.f;
      #pragma unroll
      for (int ww = 0; ww < 8; ww++){
        s += stats[ww][lane>>2][lane&3][0];
        q += stats[ww][lane>>2][lane&3][1];
      }
      float mu = s*(1.f/512.f);
      float var = q*(1.f/512.f) - mu*mu;
      murs[lane][0] = mu;
      murs[lane][1] = rsqrtf(var + 1e-5f);
    }
    __syncthreads();

    // ---- C: write h (f16) and layernorm(h) (f16) ----
    #pragma unroll
    for (int rr = 0; rr < 4; rr++){
      int row = hi*4 + rr;
      float mu = murs[row][0], rs = murs[row][1];
      #pragma unroll
      for (int i = 0; i < 4; i++){
        int j = w*64 + i*16 + lo;
        float hv = hreg[i][rr];
        WSTORE(h_s,  row, j, hv);
        WSTORE(hn_s, row, j, (hv - mu)*rs*lngv[i] + lnbv[i]);
      }
    }
    __syncthreads();

    // ---- D: hidden = relu(hn @ W_o1_top + ctx @ W_o1_bot + b_o1) ----
    #pragma unroll
    for (int i = 0; i < 4; i++){
      f32x4 acc = {0,0,0,0};
      #pragma unroll
      for (int ks = 0; ks < 16; ks++){
        half8 a = AFRAG(hn_s, abase, ks);
        acc = MFMA(a, PK[(TB_O1H + (w*4+i)*16 + ks)*64 + lane], acc);
      }
      #pragma unroll
      for (int ks = 0; ks < 8; ks++){
        half8 a = AFRAG(c_s, cbase, ks);
        acc = MFMA(a, PK[(TB_O1C + (w*4+i)*8 + ks)*64 + lane], acc);
      }
      #pragma unroll
      for (int rr = 0; rr < 4; rr++){
        int row = hi*4 + rr, j = w*64 + i*16 + lo;
        WSTORE(xh_s, row, j, fmaxf(acc[rr] + bo1v[i], 0.f));
      }
    }
    __syncthreads();

    // ---- E: logits = hidden @ W_o2 + b_o2 (waves 0-3), store out ----
    if (w < 4){
      f32x4 acc = {0,0,0,0};
      #pragma unroll
      for (int ks = 0; ks < 16; ks++){
        half8 a = AFRAG(xh_s, abase, ks);
        acc = MFMA(a, PK[(TB_O2 + w*16 + ks)*64 + lane], acc);
      }
      #pragma unroll
      for (int rr = 0; rr < 4; rr++){
        int row = hi*4 + rr, j = w*16 + lo;
        float v = acc[rr] + bo2v;
        lg_s[row*64 + j] = v;
        out[((r0 + row)*128 + t)*64 + j] = v;
      }
    }
    __syncthreads();

    // ---- F: argmax (first-max tie rule, exact jnp semantics), wave 0 ----
    if (w == 0){
      #pragma unroll 1
      for (int r2 = 0; r2 < 16; r2++){
        float v = lg_s[r2*64 + lane];
        int idx = lane;
        #pragma unroll
        for (int d = 1; d < 64; d <<= 1){
          float ov = __shfl_xor(v, d);
          int oi = __shfl_xor(idx, d);
          if (ov > v || (ov == v && oi < idx)){ v = ov; idx = oi; }
        }
        if (lane == 0) pb[r2] = idx;
      }
    }
    __syncthreads();
  }
}

extern "C" void kernel_launch(void* const* d_in, const int* in_sizes, int n_in,
                              void* d_out, int out_size, void* d_ws, size_t ws_size,
                              hipStream_t stream)
{
  const float* ctx    = (const float*)d_in[0];
  const int*   bh     = (const int*)d_in[1];    // int64 in reference -> pushed as int32
  const float* E      = (const float*)d_in[2];
  const float* W_in   = (const float*)d_in[3];
  const float* b_in   = (const float*)d_in[4];
  const float* W_init = (const float*)d_in[5];
  const float* b_init = (const float*)d_in[6];
  const float* W_ih   = (const float*)d_in[7];
  const float* W_hh   = (const float*)d_in[8];
  const float* b_ih   = (const float*)d_in[9];
  const float* b_hh   = (const float*)d_in[10];
  const float* ln_g   = (const float*)d_in[11];
  const float* ln_b   = (const float*)d_in[12];
  const float* W_o1   = (const float*)d_in[13];
  const float* b_o1   = (const float*)d_in[14];
  const float* W_o2   = (const float*)d_in[15];
  const float* b_o2   = (const float*)d_in[16];
  float* out = (float*)d_out;

  _Float16* pk   = (_Float16*)d_ws;
  float*    Etab = (float*)((char*)d_ws + WS_ETAB);
  float*    h0w  = (float*)((char*)d_ws + WS_H0);

  hipLaunchKernelGGL(pack_k, dim3(NTILES), dim3(64), 0, stream, W_in, W_ih, W_hh, W_o1, W_o2, pk);
  hipLaunchKernelGGL(etab_k, dim3(64), dim3(256), 0, stream, E, W_in, b_in, Etab);
  hipLaunchKernelGGL(h0_k, dim3(64), dim3(512), 0, stream, ctx, bh, E, W_init, b_init, h0w);
  hipLaunchKernelGGL(main_k, dim3(64), dim3(512), 0, stream, pk, Etab, h0w, ctx, bh,
                     b_ih, b_hh, ln_g, ln_b, b_o1, b_o2, out);
}

// Round 3
// 12688.500 us; speedup vs baseline: 2.4404x; 2.4404x over previous
//
#include <hip/hip_runtime.h>

typedef _Float16 half8 __attribute__((ext_vector_type(8)));
typedef float f32x4 __attribute__((ext_vector_type(4)));

#define MFMA(a,b,c) __builtin_amdgcn_mfma_f32_16x16x32_f16((a),(b),(c),0,0,0)

// packed-weight tile bases (1 tile = 16x16-output x 32-K fragment = 1024B)
#define TB_X    0      // W_in[0:256,:]   : 32 nt x 8 ks
#define TB_GI   256    // W_ih^T          : 96 nt x 16 ks
#define TB_GH   1792   // W_hh^T          : 96 nt x 16 ks
#define TB_O1H  3328   // W_o1[0:512,:]   : 32 nt x 16 ks
#define TB_O1C  3840   // W_o1[512:768,:] : 32 nt x 8 ks
#define TB_O2   4096   // W_o2            : 4 nt x 16 ks
#define NTILES  4160

#define WS_ETAB (NTILES*1024)          // 4,259,840 bytes
#define WS_H0   (WS_ETAB + 64*512*4)   // +131,072; h0w itself is 1024*512*4 = 2 MB

// ---------------- weight packing into MFMA B-fragment order ----------------
__global__ void pack_k(const float* __restrict__ W_in, const float* __restrict__ W_ih,
                       const float* __restrict__ W_hh, const float* __restrict__ W_o1,
                       const float* __restrict__ W_o2, _Float16* __restrict__ pk)
{
  int ti = blockIdx.x, lane = threadIdx.x;
  int seg = 0, nt = 0, ks = 0, r;
  if (ti < TB_GI)        { seg = 0; r = ti;          nt = r >> 3; ks = r & 7;  }
  else if (ti < TB_GH)   { seg = 1; r = ti - TB_GI;  nt = r >> 4; ks = r & 15; }
  else if (ti < TB_O1H)  { seg = 2; r = ti - TB_GH;  nt = r >> 4; ks = r & 15; }
  else if (ti < TB_O1C)  { seg = 3; r = ti - TB_O1H; nt = r >> 4; ks = r & 15; }
  else if (ti < TB_O2)   { seg = 4; r = ti - TB_O1C; nt = r >> 3; ks = r & 7;  }
  else                   { seg = 5; r = ti - TB_O2;  nt = r >> 4; ks = r & 15; }
  int n  = nt*16 + (lane & 15);
  int kb = ks*32 + (lane >> 4)*8;
  half8 v;
  #pragma unroll
  for (int e = 0; e < 8; e++){
    int k = kb + e; float f;
    if      (seg == 0) f = W_in[k*512 + n];
    else if (seg == 1) f = W_ih[n*512 + k];       // transpose: B[k][n]=W_ih[n][k]
    else if (seg == 2) f = W_hh[n*512 + k];
    else if (seg == 3) f = W_o1[k*512 + n];
    else if (seg == 4) f = W_o1[(512 + k)*512 + n];
    else               f = W_o2[k*64 + n];
    v[e] = (_Float16)f;
  }
  *(half8*)(pk + (long)ti*512 + lane*8) = v;
}

// ---------------- Etab[e][j] = E[e,:] @ W_in[256:512, j] + b_in[j] ----------------
__global__ void etab_k(const float* __restrict__ E, const float* __restrict__ W_in,
                       const float* __restrict__ b_in, float* __restrict__ Etab)
{
  int e = blockIdx.x, tid = threadIdx.x;
  __shared__ float er[256];
  if (tid < 256) er[tid] = E[e*256 + tid];
  __syncthreads();
  for (int j = tid; j < 512; j += 256){
    float acc = b_in[j];
    for (int k = 0; k < 256; k++) acc += er[k] * W_in[(256 + k)*512 + j];
    Etab[e*512 + j] = acc;
  }
}

// ---------------- h0 = tanh([ctx_mean, hist_emb] @ W_init + b_init), fp32 ----------------
__global__ __launch_bounds__(512) void h0_k(const float* __restrict__ ctx,
    const int* __restrict__ bh, const float* __restrict__ E,
    const float* __restrict__ W_init, const float* __restrict__ b_init,
    float* __restrict__ h0w)
{
  int b0 = blockIdx.x * 16, tid = threadIdx.x;
  __shared__ float cat[16][512];
  int c = tid & 255, rh = tid >> 8;
  for (int rr = 0; rr < 8; rr++){
    int r2 = rh*8 + rr;
    const float* p = ctx + ((b0 + r2)*128)*256 + c;
    float acc = 0.f;
    for (int t = 0; t < 128; t++) acc += p[t*256];
    cat[r2][c] = acc * (1.f/128.f);
    float s = 0.f;
    #pragma unroll
    for (int hh = 0; hh < 8; hh++){
      int e = bh[(b0 + r2)*8 + hh];
      s += E[e*256 + c];
    }
    cat[r2][256 + c] = s * 0.125f;
  }
  __syncthreads();
  int j = tid;
  float acc[16];
  #pragma unroll
  for (int r2 = 0; r2 < 16; r2++) acc[r2] = b_init[j];
  for (int k = 0; k < 512; k++){
    float wv = W_init[k*512 + j];
    #pragma unroll
    for (int r2 = 0; r2 < 16; r2++) acc[r2] += cat[r2][k] * wv;
  }
  #pragma unroll
  for (int r2 = 0; r2 < 16; r2++) h0w[(b0 + r2)*512 + j] = tanhf(acc[r2]);
}

// ---------------- main persistent scan kernel: 64 WGs x 512 thr, 16 rows each ----------------
#define AFRAG(buf, base, ks) (*(const half8*)((const char*)(buf) + ((((base) + (ks)*64)) ^ aswz)))
#define WSTORE(buf, row, j, val) \
  *(_Float16*)((char*)(buf) + ((((row)*1024 + (j)*2)) ^ ((((row)&7))<<4))) = (_Float16)(val)

// phase-B slot loads: slot s -> (i = s>>4, ks = s&15); 6 streams at tile offsets
// T0 + {0,512,1024,1536,2048,2560}, T0 = TB_GI + (w*4+i)*16 + ks
#define LOADB(s) do{ \
    const int T0_ = TB_GI + (w*4 + ((s)>>4))*16 + ((s)&15); \
    bb[(s)&3][0] = PK[(T0_       )*64 + lane]; \
    bb[(s)&3][1] = PK[(T0_ +  512)*64 + lane]; \
    bb[(s)&3][2] = PK[(T0_ + 1024)*64 + lane]; \
    bb[(s)&3][3] = PK[(T0_ + 1536)*64 + lane]; \
    bb[(s)&3][4] = PK[(T0_ + 2048)*64 + lane]; \
    bb[(s)&3][5] = PK[(T0_ + 2560)*64 + lane]; \
  }while(0)

#define LOADX(s) do{ \
    dq[(s)&1][0] = PK[(TB_X + (w*4+0)*8 + (s))*64 + lane]; \
    dq[(s)&1][1] = PK[(TB_X + (w*4+1)*8 + (s))*64 + lane]; \
    dq[(s)&1][2] = PK[(TB_X + (w*4+2)*8 + (s))*64 + lane]; \
    dq[(s)&1][3] = PK[(TB_X + (w*4+3)*8 + (s))*64 + lane]; \
  }while(0)

#define LOADD(s) do{ \
    dq[(s)&1][0] = PK[(TB_O1H + (w*4+0)*16 + (s))*64 + lane]; \
    dq[(s)&1][1] = PK[(TB_O1H + (w*4+1)*16 + (s))*64 + lane]; \
    dq[(s)&1][2] = PK[(TB_O1H + (w*4+2)*16 + (s))*64 + lane]; \
    dq[(s)&1][3] = PK[(TB_O1H + (w*4+3)*16 + (s))*64 + lane]; \
  }while(0)

#define LOADC(s) do{ \
    dq[(s)&1][0] = PK[(TB_O1C + (w*4+0)*8 + (s))*64 + lane]; \
    dq[(s)&1][1] = PK[(TB_O1C + (w*4+1)*8 + (s))*64 + lane]; \
    dq[(s)&1][2] = PK[(TB_O1C + (w*4+2)*8 + (s))*64 + lane]; \
    dq[(s)&1][3] = PK[(TB_O1C + (w*4+3)*8 + (s))*64 + lane]; \
  }while(0)

__global__ __launch_bounds__(512) void main_k(
    const _Float16* __restrict__ pk, const float* __restrict__ Etab,
    const float* __restrict__ h0w, const float* __restrict__ ctx,
    const int* __restrict__ bh, const float* __restrict__ b_ih,
    const float* __restrict__ b_hh, const float* __restrict__ lng,
    const float* __restrict__ lnb, const float* __restrict__ b_o1,
    const float* __restrict__ b_o2, float* __restrict__ out)
{
  const int g = blockIdx.x, tid = threadIdx.x;
  const int w = tid >> 6, lane = tid & 63, lo = lane & 15, hi = lane >> 4;
  const int r0 = g*16;

  __shared__ __align__(16) _Float16 h_s [16*512];  // h_{t-1}, f16 (A for gh)
  __shared__ __align__(16) _Float16 xh_s[16*512];  // x, then hidden (A for gi / o2)
  __shared__ __align__(16) _Float16 hn_s[16*512];  // layernorm(h) (A for o1)
  __shared__ __align__(16) _Float16 c_s [16*256];  // ctx_t f16 (A for x / o1c)
  __shared__ float lg_s[16*64];
  __shared__ float stats[8][4][4][2];
  __shared__ float murs[16][2];
  __shared__ int   pb[16];

  // combined biases for r,z gates; separate for n gate
  float bcr[4], bcz[4], bin_[4], bhn[4], bo1v[4], lngv[4], lnbv[4];
  #pragma unroll
  for (int i = 0; i < 4; i++){
    int j = w*64 + i*16 + lo;
    bcr[i] = b_ih[j]      + b_hh[j];
    bcz[i] = b_ih[512+j]  + b_hh[512+j];
    bin_[i]= b_ih[1024+j];
    bhn[i] = b_hh[1024+j];
    bo1v[i]= b_o1[j]; lngv[i]= lng[j]; lnbv[i]= lnb[j];
  }
  const float bo2v = (w < 4) ? b_o2[w*16 + lo] : 0.f;

  // h state in fp32 registers: wave w owns cols [w*64, w*64+64)
  float hreg[4][4];
  #pragma unroll
  for (int i = 0; i < 4; i++)
    #pragma unroll
    for (int rr = 0; rr < 4; rr++)
      hreg[i][rr] = h0w[(r0 + hi*4 + rr)*512 + w*64 + i*16 + lo];

  // stage h0 -> h_s (f16, swizzled)
  #pragma unroll
  for (int c2 = 0; c2 < 2; c2++){
    int ch = tid*2 + c2, rr = ch >> 6, c8 = ch & 63;
    const float* p = h0w + (r0 + rr)*512 + c8*8;
    half8 v;
    #pragma unroll
    for (int e = 0; e < 8; e++) v[e] = (_Float16)p[e];
    *(half8*)((char*)h_s + (((rr*1024 + c8*16)) ^ ((rr&7)<<4))) = v;
  }
  if (tid < 16) pb[tid] = bh[(r0 + tid)*8 + 7];
  __syncthreads();

  const int aswz  = (lo & 7) << 4;
  const int abase = lo*1024 + hi*16;
  const int cbase = lo*512  + hi*16;
  const half8* PK = (const half8*)pk;

  #pragma unroll 1
  for (int t = 0; t < 128; t++){
    // ---- A1: stage ctx_t (f32 -> f16 LDS, swizzled) ----
    {
      int rr = tid >> 5, c8 = tid & 31;
      const float* p = ctx + ((r0 + rr)*128 + t)*256 + c8*8;
      half8 v;
      #pragma unroll
      for (int e = 0; e < 8; e++) v[e] = (_Float16)p[e];
      *(half8*)((char*)c_s + (((rr*512 + c8*16)) ^ ((rr&7)<<4))) = v;
    }
    __syncthreads();

    // ---- A2: x = relu(ctx @ W_in_top + Etab[pb]) ---- (pipelined, lookahead 2)
    {
      float et[4][4];
      #pragma unroll
      for (int rr = 0; rr < 4; rr++){
        int e = pb[hi*4 + rr];
        #pragma unroll
        for (int i = 0; i < 4; i++) et[i][rr] = Etab[e*512 + w*64 + i*16 + lo];
      }
      half8 dq[2][4];
      f32x4 acc[4];
      const f32x4 z4 = {0.f,0.f,0.f,0.f};
      #pragma unroll
      for (int i = 0; i < 4; i++) acc[i] = z4;
      LOADX(0); LOADX(1);
      #pragma unroll
      for (int s = 0; s < 8; s++){
        half8 a = AFRAG(c_s, cbase, s);
        acc[0] = MFMA(a, dq[s&1][0], acc[0]);
        acc[1] = MFMA(a, dq[s&1][1], acc[1]);
        acc[2] = MFMA(a, dq[s&1][2], acc[2]);
        acc[3] = MFMA(a, dq[s&1][3], acc[3]);
        if (s + 2 < 8) LOADX(s+2);
      }
      #pragma unroll
      for (int i = 0; i < 4; i++)
        #pragma unroll
        for (int rr = 0; rr < 4; rr++){
          int row = hi*4 + rr, j = w*64 + i*16 + lo;
          WSTORE(xh_s, row, j, fmaxf(acc[i][rr] + et[i][rr], 0.f));
        }
    }
    __syncthreads();

    // ---- B: gi/gh MFMA (lookahead-4 pipeline) + GRU gates (fp32) ----
    {
      float srow[4] = {0,0,0,0}, sqrow[4] = {0,0,0,0};
      half8 bb[4][6];
      f32x4 a0,a1,a2,a3,a4,a5;
      const f32x4 z4 = {0.f,0.f,0.f,0.f};
      LOADB(0); LOADB(1); LOADB(2); LOADB(3);
      #pragma unroll
      for (int s = 0; s < 64; s++){
        const int i = s >> 4, ks = s & 15;
        if (ks == 0){ a0=z4; a1=z4; a2=z4; a3=z4; a4=z4; a5=z4; }
        half8 ax = AFRAG(xh_s, abase, ks);
        half8 ah = AFRAG(h_s,  abase, ks);
        a0 = MFMA(ax, bb[s&3][0], a0);
        a1 = MFMA(ax, bb[s&3][1], a1);
        a2 = MFMA(ax, bb[s&3][2], a2);
        a3 = MFMA(ah, bb[s&3][3], a3);
        a4 = MFMA(ah, bb[s&3][4], a4);
        a5 = MFMA(ah, bb[s&3][5], a5);
        if (s + 4 < 64) LOADB(s+4);
        if (ks == 15){
          #pragma unroll
          for (int rr = 0; rr < 4; rr++){
            float rg = 1.f/(1.f + __expf(-(a0[rr] + a3[rr] + bcr[i])));
            float zg = 1.f/(1.f + __expf(-(a1[rr] + a4[rr] + bcz[i])));
            float aa = (a2[rr] + bin_[i]) + rg*(a5[rr] + bhn[i]);
            float ea = __expf(-2.f*fabsf(aa));
            float th = (1.f - ea)/(1.f + ea);
            float ng = (aa < 0.f) ? -th : th;
            float hv = (1.f - zg)*ng + zg*hreg[i][rr];
            hreg[i][rr] = hv;
            srow[rr] += hv; sqrow[rr] += hv*hv;
          }
        }
      }
      #pragma unroll
      for (int d = 1; d < 16; d <<= 1){
        #pragma unroll
        for (int rr = 0; rr < 4; rr++){
          srow[rr]  += __shfl_xor(srow[rr],  d);
          sqrow[rr] += __shfl_xor(sqrow[rr], d);
        }
      }
      if (lo == 0){
        #pragma unroll
        for (int rr = 0; rr < 4; rr++){
          stats[w][hi][rr][0] = srow[rr];
          stats[w][hi][rr][1] = sqrow[rr];
        }
      }
    }
    __syncthreads();
    if (w == 0 && lane < 16){
      float s = 0.f, q = 0.f;
      #pragma unroll
      for (int ww = 0; ww < 8; ww++){
        s += stats[ww][lane>>2][lane&3][0];
        q += stats[ww][lane>>2][lane&3][1];
      }
      float mu = s*(1.f/512.f);
      float var = q*(1.f/512.f) - mu*mu;
      murs[lane][0] = mu;
      murs[lane][1] = rsqrtf(var + 1e-5f);
    }
    __syncthreads();

    // ---- C: write h (f16) and layernorm(h) (f16) ----
    #pragma unroll
    for (int rr = 0; rr < 4; rr++){
      int row = hi*4 + rr;
      float mu = murs[row][0], rs = murs[row][1];
      #pragma unroll
      for (int i = 0; i < 4; i++){
        int j = w*64 + i*16 + lo;
        float hv = hreg[i][rr];
        WSTORE(h_s,  row, j, hv);
        WSTORE(hn_s, row, j, (hv - mu)*rs*lngv[i] + lnbv[i]);
      }
    }
    __syncthreads();

    // ---- D: hidden = relu(hn @ W_o1_top + ctx @ W_o1_bot + b_o1) ---- (pipelined)
    {
      half8 dq[2][4];
      f32x4 acc[4];
      const f32x4 z4 = {0.f,0.f,0.f,0.f};
      #pragma unroll
      for (int i = 0; i < 4; i++) acc[i] = z4;
      LOADD(0); LOADD(1);
      #pragma unroll
      for (int s = 0; s < 16; s++){
        half8 a = AFRAG(hn_s, abase, s);
        acc[0] = MFMA(a, dq[s&1][0], acc[0]);
        acc[1] = MFMA(a, dq[s&1][1], acc[1]);
        acc[2] = MFMA(a, dq[s&1][2], acc[2]);
        acc[3] = MFMA(a, dq[s&1][3], acc[3]);
        if (s + 2 < 16) LOADD(s+2);
        else if (s == 14) LOADC(0);
        else LOADC(1);
      }
      #pragma unroll
      for (int s = 0; s < 8; s++){
        half8 a = AFRAG(c_s, cbase, s);
        acc[0] = MFMA(a, dq[s&1][0], acc[0]);
        acc[1] = MFMA(a, dq[s&1][1], acc[1]);
        acc[2] = MFMA(a, dq[s&1][2], acc[2]);
        acc[3] = MFMA(a, dq[s&1][3], acc[3]);
        if (s + 2 < 8) LOADC(s+2);
      }
      #pragma unroll
      for (int i = 0; i < 4; i++)
        #pragma unroll
        for (int rr = 0; rr < 4; rr++){
          int row = hi*4 + rr, j = w*64 + i*16 + lo;
          WSTORE(xh_s, row, j, fmaxf(acc[i][rr] + bo1v[i], 0.f));
        }
    }
    __syncthreads();

    // ---- E: logits = hidden @ W_o2 + b_o2 (waves 0-3, all frags preloaded) ----
    if (w < 4){
      half8 eb[16];
      #pragma unroll
      for (int ks = 0; ks < 16; ks++) eb[ks] = PK[(TB_O2 + w*16 + ks)*64 + lane];
      f32x4 acc = {0,0,0,0};
      #pragma unroll
      for (int ks = 0; ks < 16; ks++){
        half8 a = AFRAG(xh_s, abase, ks);
        acc = MFMA(a, eb[ks], acc);
      }
      #pragma unroll
      for (int rr = 0; rr < 4; rr++){
        int row = hi*4 + rr, j = w*16 + lo;
        lg_s[row*64 + j] = acc[rr] + bo2v;
      }
    }
    __syncthreads();

    // ---- F: out store (coalesced) + argmax, 2 rows per wave ----
    {
      #pragma unroll
      for (int sub = 0; sub < 2; sub++){
        int r2 = w*2 + sub;
        float v = lg_s[r2*64 + lane];
        out[((r0 + r2)*128 + t)*64 + lane] = v;
        int idx = lane;
        #pragma unroll
        for (int d = 1; d < 64; d <<= 1){
          float ov = __shfl_xor(v, d);
          int oi = __shfl_xor(idx, d);
          if (ov > v || (ov == v && oi < idx)){ v = ov; idx = oi; }
        }
        if (lane == 0) pb[r2] = idx;
      }
    }
    __syncthreads();
  }
}

extern "C" void kernel_launch(void* const* d_in, const int* in_sizes, int n_in,
                              void* d_out, int out_size, void* d_ws, size_t ws_size,
                              hipStream_t stream)
{
  const float* ctx    = (const float*)d_in[0];
  const int*   bh     = (const int*)d_in[1];    // int64 in reference -> pushed as int32
  const float* E      = (const float*)d_in[2];
  const float* W_in   = (const float*)d_in[3];
  const float* b_in   = (const float*)d_in[4];
  const float* W_init = (const float*)d_in[5];
  const float* b_init = (const float*)d_in[6];
  const float* W_ih   = (const float*)d_in[7];
  const float* W_hh   = (const float*)d_in[8];
  const float* b_ih   = (const float*)d_in[9];
  const float* b_hh   = (const float*)d_in[10];
  const float* ln_g   = (const float*)d_in[11];
  const float* ln_b   = (const float*)d_in[12];
  const float* W_o1   = (const float*)d_in[13];
  const float* b_o1   = (const float*)d_in[14];
  const float* W_o2   = (const float*)d_in[15];
  const float* b_o2   = (const float*)d_in[16];
  float* out = (float*)d_out;

  _Float16* pk   = (_Float16*)d_ws;
  float*    Etab = (float*)((char*)d_ws + WS_ETAB);
  float*    h0w  = (float*)((char*)d_ws + WS_H0);

  hipLaunchKernelGGL(pack_k, dim3(NTILES), dim3(64), 0, stream, W_in, W_ih, W_hh, W_o1, W_o2, pk);
  hipLaunchKernelGGL(etab_k, dim3(64), dim3(256), 0, stream, E, W_in, b_in, Etab);
  hipLaunchKernelGGL(h0_k, dim3(64), dim3(512), 0, stream, ctx, bh, E, W_init, b_init, h0w);
  hipLaunchKernelGGL(main_k, dim3(64), dim3(512), 0, stream, pk, Etab, h0w, ctx, bh,
                     b_ih, b_hh, ln_g, ln_b, b_o1, b_o2, out);
}